// Round 3
// baseline (296.986 us; speedup 1.0000x reference)
//
#include <hip/hip_runtime.h>

#define EDIM 128
#define PRIME_BLOCKS 256

// Fast log_sigmoid: min(x,0) - log(1+exp(-|x|)) with hw v_exp_f32/v_log_f32.
__device__ __forceinline__ float fast_logsig(float x) {
    return fminf(x, 0.0f) - __logf(1.0f + __expf(-fabsf(x)));
}

// Gather structure identical to the 90 us round-2 kernel (half-wave float4
// rows, scalar s_load index prefetch). New: the first PRIME_BLOCKS blocks
// (dispatched first) linearly stream both embedding tables once, so the
// compulsory ~205 MB of HBM traffic is fetched at sequential-stream
// efficiency into the 256 MB LLC (both tables fit), instead of trickling in
// as random 512 B granules over the whole kernel. Gather waves then hit LLC.
__global__ __launch_bounds__(256) void sgns_loss_kernel(
    const float* __restrict__ second_emb,
    const float* __restrict__ context_emb,
    const int* __restrict__ v_i,
    const int* __restrict__ v_j,
    const int* __restrict__ negs,
    float* __restrict__ out,
    int B,
    int tbl_n4)   // float4 count per embedding table
{
    // ---------------- LLC prime blocks ----------------
    if (blockIdx.x < PRIME_BLOCKS) {
        const int ptid    = blockIdx.x * blockDim.x + threadIdx.x;
        const int pstride = PRIME_BLOCKS * blockDim.x;
        const float4* __restrict__ c4 = (const float4*)context_emb;
        const float4* __restrict__ s4 = (const float4*)second_emb;
        float sx = 0.0f, sy = 0.0f, sz = 0.0f, sw = 0.0f;
        // context first: ~98% of its rows are touched by the gathers
        for (int k = ptid; k < tbl_n4; k += pstride) {
            const float4 a = c4[k];
            sx += a.x; sy += a.y; sz += a.z; sw += a.w;
        }
        for (int k = ptid; k < tbl_n4; k += pstride) {
            const float4 a = s4[k];
            sx += a.x; sy += a.y; sz += a.z; sw += a.w;
        }
        const float sink = sx + sy + sz + sw;
        asm volatile("" :: "v"(sink));   // keep loads live, no store
        return;
    }

    // ---------------- gather blocks (identical to round 2) ----------------
    const int lane   = threadIdx.x & 63;
    const int half   = lane >> 5;
    const int sub    = lane & 31;
    const int gwave  = (((int)blockIdx.x - PRIME_BLOCKS) * blockDim.x
                        + threadIdx.x) >> 6;
    const int nwaves = (((int)gridDim.x - PRIME_BLOCKS) * blockDim.x) >> 6;
    const int step   = nwaves * 4;

    const float4* __restrict__ A = (const float4*)second_emb;
    const float4* __restrict__ C = (const float4*)context_emb;

    float acc = 0.0f;

#define LOAD_IDX(BB, VI, VJ, N0, N1, N2, N3, N4) do {            \
        const int ub_ = __builtin_amdgcn_readfirstlane(BB);      \
        VI = *(const int4*)(v_i + ub_);                          \
        VJ = *(const int4*)(v_j + ub_);                          \
        N0 = *(const int4*)(negs + 0 * (size_t)B + ub_);         \
        N1 = *(const int4*)(negs + 1 * (size_t)B + ub_);         \
        N2 = *(const int4*)(negs + 2 * (size_t)B + ub_);         \
        N3 = *(const int4*)(negs + 3 * (size_t)B + ub_);         \
        N4 = *(const int4*)(negs + 4 * (size_t)B + ub_);         \
    } while (0)

#define ROW(TBL, IDX) (TBL)[(((size_t)(uint32_t)(IDX)) << 5) + sub]

    int base = gwave * 4;   // B % 4 == 0
    if (base < B) {
        int4 cvi, cvj, cn0, cn1, cn2, cn3, cn4;
        LOAD_IDX(base, cvi, cvj, cn0, cn1, cn2, cn3, cn4);

        for (;;) {
            const int i0  = half ? cvi.z : cvi.x;
            const int i1  = half ? cvi.w : cvi.y;
            const int j0  = half ? cvj.z : cvj.x;
            const int j1  = half ? cvj.w : cvj.y;
            const int n00 = half ? cn0.z : cn0.x;
            const int n01 = half ? cn1.z : cn1.x;
            const int n02 = half ? cn2.z : cn2.x;
            const int n03 = half ? cn3.z : cn3.x;
            const int n04 = half ? cn4.z : cn4.x;
            const int n10 = half ? cn0.w : cn0.y;
            const int n11 = half ? cn1.w : cn1.y;
            const int n12 = half ? cn2.w : cn2.y;
            const int n13 = half ? cn3.w : cn3.y;
            const int n14 = half ? cn4.w : cn4.y;

            const float4 a0  = ROW(A, i0);
            const float4 p0  = ROW(C, j0);
            const float4 q00 = ROW(C, n00);
            const float4 q01 = ROW(C, n01);
            const float4 q02 = ROW(C, n02);
            const float4 q03 = ROW(C, n03);
            const float4 q04 = ROW(C, n04);
            const float4 a1  = ROW(A, i1);
            const float4 p1  = ROW(C, j1);
            const float4 q10 = ROW(C, n10);
            const float4 q11 = ROW(C, n11);
            const float4 q12 = ROW(C, n12);
            const float4 q13 = ROW(C, n13);
            const float4 q14 = ROW(C, n14);

            const int  nb   = base + step;
            const bool more = (nb < B);
            int4 nvi = cvi, nvj = cvj, nn0 = cn0, nn1 = cn1,
                 nn2 = cn2, nn3 = cn3, nn4 = cn4;
            if (more) LOAD_IDX(nb, nvi, nvj, nn0, nn1, nn2, nn3, nn4);

            float d[12];
            d[0]  = a0.x * p0.x  + a0.y * p0.y  + a0.z * p0.z  + a0.w * p0.w;
            d[1]  = a0.x * q00.x + a0.y * q00.y + a0.z * q00.z + a0.w * q00.w;
            d[2]  = a0.x * q01.x + a0.y * q01.y + a0.z * q01.z + a0.w * q01.w;
            d[3]  = a0.x * q02.x + a0.y * q02.y + a0.z * q02.z + a0.w * q02.w;
            d[4]  = a0.x * q03.x + a0.y * q03.y + a0.z * q03.z + a0.w * q03.w;
            d[5]  = a0.x * q04.x + a0.y * q04.y + a0.z * q04.z + a0.w * q04.w;
            d[6]  = a1.x * p1.x  + a1.y * p1.y  + a1.z * p1.z  + a1.w * p1.w;
            d[7]  = a1.x * q10.x + a1.y * q10.y + a1.z * q10.z + a1.w * q10.w;
            d[8]  = a1.x * q11.x + a1.y * q11.y + a1.z * q11.z + a1.w * q11.w;
            d[9]  = a1.x * q12.x + a1.y * q12.y + a1.z * q12.z + a1.w * q12.w;
            d[10] = a1.x * q13.x + a1.y * q13.y + a1.z * q13.z + a1.w * q13.w;
            d[11] = a1.x * q14.x + a1.y * q14.y + a1.z * q14.z + a1.w * q14.w;

            #pragma unroll
            for (int off = 1; off <= 16; off <<= 1) {
                #pragma unroll
                for (int m = 0; m < 12; ++m)
                    d[m] += __shfl_xor(d[m], off);
            }

            float x = 0.0f;
            bool active = false;
            if (sub < 6) {
                x = (sub == 0) ? d[0] : -d[sub];
                active = true;
            } else if (sub >= 8 && sub < 14) {
                const int s = sub - 8;
                x = (s == 0) ? d[6] : -d[6 + s];
                active = true;
            }
            if (active) acc += fast_logsig(x);

            if (!more) break;
            base = nb;
            cvi = nvi; cvj = nvj;
            cn0 = nn0; cn1 = nn1; cn2 = nn2; cn3 = nn3; cn4 = nn4;
        }
    }

#undef ROW
#undef LOAD_IDX

    #pragma unroll
    for (int off = 32; off >= 1; off >>= 1)
        acc += __shfl_xor(acc, off);

    __shared__ float wsum[4];
    const int wid = threadIdx.x >> 6;
    if ((threadIdx.x & 63) == 0) wsum[wid] = acc;
    __syncthreads();

    if (threadIdx.x == 0) {
        const float s = wsum[0] + wsum[1] + wsum[2] + wsum[3];
        atomicAdd(out, s * (-1.0f / (float)B));
    }
}

extern "C" void kernel_launch(void* const* d_in, const int* in_sizes, int n_in,
                              void* d_out, int out_size, void* d_ws, size_t ws_size,
                              hipStream_t stream) {
    const float* second_emb  = (const float*)d_in[0];
    const float* context_emb = (const float*)d_in[1];
    const int*   v_i  = (const int*)d_in[2];
    const int*   v_j  = (const int*)d_in[3];
    const int*   negs = (const int*)d_in[4];
    float* out = (float*)d_out;
    const int B = in_sizes[2];
    const int tbl_n4 = in_sizes[0] / 4;   // float4 count per table

    // d_out is re-poisoned before every timed launch; zero it first.
    hipMemsetAsync(d_out, 0, sizeof(float), stream);

    // 256 prime blocks (dispatched first, one per CU) + 2048 gather blocks.
    dim3 block(256);
    dim3 grid(PRIME_BLOCKS + 2048);
    sgns_loss_kernel<<<grid, block, 0, stream>>>(
        second_emb, context_emb, v_i, v_j, negs, out, B, tbl_n4);
}

// Round 4
// 241.004 us; speedup vs baseline: 1.2323x; 1.2323x over previous
//
#include <hip/hip_runtime.h>

#define EDIM 128
#define KNEG 5

// Fast log_sigmoid: min(x,0) - log(1+exp(-|x|)) with hw v_exp_f32/v_log_f32.
// Absolute error < ~1e-6 per term; output is a mean over 786K terms.
__device__ __forceinline__ float fast_logsig(float x) {
    return fminf(x, 0.0f) - __logf(1.0f + __expf(-fabsf(x)));
}

// Best measured structure (86.5-87 us dispatch): half-wave (32 lanes) per
// batch element, 2 elements per half-wave per iteration -> 14 float4 row
// loads in flight (512 B coalesced per row gather). Dots reduced via 5
// shfl_xor steps (offsets 1..16 stay within the 32-lane half).
//
// Measured bracket for this problem (rocprof, MI355X):
//  - random-gather delivery is the binding resource: 470 MB logical row
//    traffic at ~5.4 TB/s delivered (2.66 TB/s HBM + LLC hits), with
//    FETCH ~= compulsory bytes. VALUBusy 14-28% across variants with no
//    effect on time; occupancy/bank-conflict/fetch all clean.
//  - LLC priming (R3) and index-path scalarization (R1/R2) both refuted
//    as wins; MLP already ~448 outstanding reqs/CU >> HW miss-queue depth.
__global__ __launch_bounds__(256) void sgns_loss_kernel(
    const float* __restrict__ second_emb,
    const float* __restrict__ context_emb,
    const int* __restrict__ v_i,
    const int* __restrict__ v_j,
    const int* __restrict__ negs,
    float* __restrict__ out,
    int B)
{
    const int tid   = blockIdx.x * blockDim.x + threadIdx.x;
    const int lane  = threadIdx.x & 63;
    const int half  = lane >> 5;   // 0 or 1: which pair this half-wave owns
    const int sub   = lane & 31;   // lane within the half-wave
    const int gwave = tid >> 6;
    const int nwaves = (gridDim.x * blockDim.x) >> 6;

    float acc = 0.0f;

    // Each wave handles 4 consecutive elements per iteration:
    // half 0 -> base+0, base+1 ; half 1 -> base+2, base+3.
    for (int base = gwave * 4; base < B; base += nwaves * 4) {
        const int b0 = base + half * 2;     // B % 4 == 0; always in-range
        const int b1 = b0 + 1;

        const int i0  = v_i[b0];
        const int i1  = v_i[b1];
        const int j0  = v_j[b0];
        const int j1  = v_j[b1];
        const int n00 = negs[0 * B + b0];
        const int n01 = negs[1 * B + b0];
        const int n02 = negs[2 * B + b0];
        const int n03 = negs[3 * B + b0];
        const int n04 = negs[4 * B + b0];
        const int n10 = negs[0 * B + b1];
        const int n11 = negs[1 * B + b1];
        const int n12 = negs[2 * B + b1];
        const int n13 = negs[3 * B + b1];
        const int n14 = negs[4 * B + b1];

        // Issue all 14 row loads up front for max memory-level parallelism
        const float4 a0  = ((const float4*)(second_emb  + (size_t)i0  * EDIM))[sub];
        const float4 a1  = ((const float4*)(second_emb  + (size_t)i1  * EDIM))[sub];
        const float4 p0  = ((const float4*)(context_emb + (size_t)j0  * EDIM))[sub];
        const float4 p1  = ((const float4*)(context_emb + (size_t)j1  * EDIM))[sub];
        const float4 q00 = ((const float4*)(context_emb + (size_t)n00 * EDIM))[sub];
        const float4 q01 = ((const float4*)(context_emb + (size_t)n01 * EDIM))[sub];
        const float4 q02 = ((const float4*)(context_emb + (size_t)n02 * EDIM))[sub];
        const float4 q03 = ((const float4*)(context_emb + (size_t)n03 * EDIM))[sub];
        const float4 q04 = ((const float4*)(context_emb + (size_t)n04 * EDIM))[sub];
        const float4 q10 = ((const float4*)(context_emb + (size_t)n10 * EDIM))[sub];
        const float4 q11 = ((const float4*)(context_emb + (size_t)n11 * EDIM))[sub];
        const float4 q12 = ((const float4*)(context_emb + (size_t)n12 * EDIM))[sub];
        const float4 q13 = ((const float4*)(context_emb + (size_t)n13 * EDIM))[sub];
        const float4 q14 = ((const float4*)(context_emb + (size_t)n14 * EDIM))[sub];

        float d[12];
        d[0]  = a0.x * p0.x  + a0.y * p0.y  + a0.z * p0.z  + a0.w * p0.w;
        d[1]  = a0.x * q00.x + a0.y * q00.y + a0.z * q00.z + a0.w * q00.w;
        d[2]  = a0.x * q01.x + a0.y * q01.y + a0.z * q01.z + a0.w * q01.w;
        d[3]  = a0.x * q02.x + a0.y * q02.y + a0.z * q02.z + a0.w * q02.w;
        d[4]  = a0.x * q03.x + a0.y * q03.y + a0.z * q03.z + a0.w * q03.w;
        d[5]  = a0.x * q04.x + a0.y * q04.y + a0.z * q04.z + a0.w * q04.w;
        d[6]  = a1.x * p1.x  + a1.y * p1.y  + a1.z * p1.z  + a1.w * p1.w;
        d[7]  = a1.x * q10.x + a1.y * q10.y + a1.z * q10.z + a1.w * q10.w;
        d[8]  = a1.x * q11.x + a1.y * q11.y + a1.z * q11.z + a1.w * q11.w;
        d[9]  = a1.x * q12.x + a1.y * q12.y + a1.z * q12.z + a1.w * q12.w;
        d[10] = a1.x * q13.x + a1.y * q13.y + a1.z * q13.z + a1.w * q13.w;
        d[11] = a1.x * q14.x + a1.y * q14.y + a1.z * q14.z + a1.w * q14.w;

        // Butterfly reduce within each 32-lane half; afterwards every lane
        // of the half holds all 12 full dot products.
        #pragma unroll
        for (int off = 1; off <= 16; off <<= 1) {
            #pragma unroll
            for (int m = 0; m < 12; ++m)
                d[m] += __shfl_xor(d[m], off);
        }

        // Distribute the 12 log_sigmoid evals: lanes 0..5 take element b0
        // (dot s), lanes 8..13 take element b1 (dot s-8+6).
        float x = 0.0f;
        bool active = false;
        if (sub < 6) {
            x = (sub == 0) ? d[0] : -d[sub];
            active = true;
        } else if (sub >= 8 && sub < 14) {
            const int s = sub - 8;
            x = (s == 0) ? d[6] : -d[6 + s];
            active = true;
        }
        if (active) acc += fast_logsig(x);
    }

    // Reduce acc over the full wave (64 lanes)
    #pragma unroll
    for (int off = 32; off >= 1; off >>= 1)
        acc += __shfl_xor(acc, off);

    __shared__ float wsum[4];
    const int wid = threadIdx.x >> 6;
    if ((threadIdx.x & 63) == 0) wsum[wid] = acc;
    __syncthreads();

    if (threadIdx.x == 0) {
        float s = wsum[0] + wsum[1] + wsum[2] + wsum[3];
        atomicAdd(out, s * (-1.0f / (float)B));
    }
}

extern "C" void kernel_launch(void* const* d_in, const int* in_sizes, int n_in,
                              void* d_out, int out_size, void* d_ws, size_t ws_size,
                              hipStream_t stream) {
    const float* second_emb  = (const float*)d_in[0];
    const float* context_emb = (const float*)d_in[1];
    const int*   v_i  = (const int*)d_in[2];
    const int*   v_j  = (const int*)d_in[3];
    const int*   negs = (const int*)d_in[4];
    float* out = (float*)d_out;
    const int B = in_sizes[2];

    // d_out is re-poisoned to 0xAA before every timed launch; zero it first.
    hipMemsetAsync(d_out, 0, sizeof(float), stream);

    // 2048 blocks x 4 waves = 8192 waves = 32 waves/CU (full wave-slot
    // occupancy at VGPR=52). Each wave covers 4 elements/iteration.
    dim3 block(256);
    dim3 grid(2048);
    sgns_loss_kernel<<<grid, block, 0, stream>>>(
        second_emb, context_emb, v_i, v_j, negs, out, B);
}